// Round 1
// 402.717 us; speedup vs baseline: 1.1763x; 1.1763x over previous
//
#include <hip/hip_runtime.h>
#include <math.h>

// StyleGAN2 StyledConvUp, B=16, Cin=Cout=512, 32x32 -> 64x64. fp32 I/O.
// Round 5: clean-GEMM reframe. Conv-transpose computed as ONE GEMM:
//   T[t*512+oc][b*1024+px] = sum_ic W[t,oc,ic] * xs[b,px,ic]
//   (M=4608, N=16384, K=512; tap dim moved into M -> B amortized over taps)
// Parity/shift tap-summation + blur + noise + bias + lrelu fused in k_blur:
//   I[p=(py,px)][uy][ux] = sum_{(ky,kx) in parity p} T[ky*3+kx][uy-(ky==2)][ux-(kx==2)]
// GEMM: 128x256 block, 4 waves of 64x128, BK=64, XOR-swizzled LDS (conflict-free),
// coalesced 128B staging segments, no bounds checks (exact tiling).

typedef __attribute__((ext_vector_type(8))) __bf16 bf16x8;
typedef __attribute__((ext_vector_type(4))) float f32x4;

#define WSCALE 0.014731391274719739f      /* 1/sqrt(512*9) */
#define SSCALE 0.044194173824159216f      /* 1/sqrt(512)   */

__device__ __forceinline__ unsigned short f2bf(float f) {
  unsigned u = __builtin_bit_cast(unsigned, f);
  u += 0x7fff + ((u >> 16) & 1);             // RTNE, finite inputs
  return (unsigned short)(u >> 16);
}
__device__ __forceinline__ float bf2f(unsigned short h) {
  unsigned u = ((unsigned)h) << 16;
  return __builtin_bit_cast(float, u);
}

// ---- s[b,ic] ----
__global__ __launch_bounds__(256) void k_style(
    const float* __restrict__ style, const float* __restrict__ mod_w,
    const float* __restrict__ mod_b, float* __restrict__ s_out) {
  int wid  = (blockIdx.x * 256 + threadIdx.x) >> 6;
  int lane = threadIdx.x & 63;
  int b = wid >> 9, ic = wid & 511;
  float acc = 0.f;
  for (int j = lane; j < 512; j += 64)
    acc += style[b * 512 + j] * mod_w[ic * 512 + j];
  for (int off = 32; off > 0; off >>= 1) acc += __shfl_down(acc, off);
  if (lane == 0) s_out[b * 512 + ic] = acc * SSCALE + mod_b[ic];
}

// ---- W2[(tg*512+oc)][ic] bf16 (GEMM A) + W2S[oc][ic] = sum_t w^2 ----
__global__ __launch_bounds__(256) void k_w2(
    const float* __restrict__ conv_w, unsigned short* __restrict__ W2,
    float* __restrict__ w2s) {
  __shared__ float t[4608];
  const int oc = blockIdx.x;
  for (int i = threadIdx.x; i < 4608; i += 256) t[i] = conv_w[oc * 4608 + i];
  __syncthreads();
  for (int i = threadIdx.x; i < 4608; i += 256) {
    int tg = i >> 9, ic = i & 511;
    W2[((size_t)(tg * 512 + oc)) * 512 + ic] = f2bf(t[ic * 9 + tg]);
  }
  for (int i = threadIdx.x; i < 512; i += 256) {
    float a = 0.f;
    #pragma unroll
    for (int tg = 0; tg < 9; tg++) { float w = t[i * 9 + tg]; a += w * w; }
    w2s[oc * 512 + i] = a;
  }
}

// ---- dscale[b,oc] (uses precomputed per-(oc,ic) squared-weight sums) ----
__global__ __launch_bounds__(256) void k_demod(
    const float* __restrict__ w2s, const float* __restrict__ s,
    float* __restrict__ dscale) {
  int wid  = (blockIdx.x * 256 + threadIdx.x) >> 6;
  int lane = threadIdx.x & 63;
  int b = wid >> 9, oc = wid & 511;
  float acc = 0.f;
  for (int ic = lane; ic < 512; ic += 64) {
    float sv = s[b * 512 + ic];
    acc += sv * sv * w2s[oc * 512 + ic];
  }
  for (int off = 32; off > 0; off >>= 1) acc += __shfl_down(acc, off);
  if (lane == 0)
    dscale[b * 512 + oc] = WSCALE * rsqrtf(WSCALE * WSCALE * acc + 1e-8f);
}

// ---- S2[b][px(1024)][ic(512)] = x*s, pixel-major bf16 (GEMM B, unpadded) ----
__global__ __launch_bounds__(256) void k_xs(
    const float* __restrict__ x, const float* __restrict__ s,
    unsigned short* __restrict__ S2) {
  __shared__ float xt[64][65];
  const int b = blockIdx.z, ic0 = blockIdx.y * 64, r0 = blockIdx.x * 2;
  for (int i = threadIdx.x; i < 4096; i += 256) {
    int icL = i >> 6, pxL = i & 63;
    int gr = r0 + (pxL >> 5), gc = pxL & 31;
    xt[icL][pxL] = x[((b * 512 + ic0 + icL) * 32 + gr) * 32 + gc] * s[b * 512 + ic0 + icL];
  }
  __syncthreads();
  for (int i = threadIdx.x; i < 512; i += 256) {
    int pxL = i >> 3, icO = i & 7;
    unsigned short tmp[8];
    #pragma unroll
    for (int k = 0; k < 8; k++) tmp[k] = f2bf(xt[icO * 8 + k][pxL]);
    int gr = r0 + (pxL >> 5), gc = pxL & 31;
    *(uint4*)(&S2[((size_t)b * 1024 + gr * 32 + gc) * 512 + ic0 + icO * 8]) =
        *(const uint4*)tmp;
  }
}

// ---- GEMM: C[4608][16384] = W2 * S2^T, block 128(M) x 256(N), BK=64 ----
// LDS rows are 128B (full bank cycle); 16B k-chunk slot is XOR-swizzled by
// (row&7) so staging writes and fragment reads are both <=2-way (free).
__global__ __launch_bounds__(256, 2) void k_gemm(
    const unsigned short* __restrict__ S2, const unsigned short* __restrict__ W2,
    const float* __restrict__ dscale, unsigned short* __restrict__ T, int b_base) {
  __shared__ __align__(16) unsigned short As[128][64];   // 16 KB
  __shared__ __align__(16) unsigned short Bs[256][64];   // 32 KB

  const int mt = blockIdx.x;                 // 0..35  (t = mt>>2, oc-block = mt&3)
  const int nt = blockIdx.y;                 // 0..3   (px-block within batch)
  const int bl = blockIdx.z, b = b_base + bl;
  const int m0 = mt * 128;
  const int tid = threadIdx.x, lane = tid & 63;
  const int wv = tid >> 6, wm = wv >> 1, wn = wv & 1;
  const int l15 = lane & 15, quad = lane >> 4;

  const unsigned short* __restrict__ Ag = W2 + (size_t)m0 * 512;
  const unsigned short* __restrict__ Bg = S2 + ((size_t)b * 1024 + nt * 256) * 512;

  f32x4 acc[4][8];
  #pragma unroll
  for (int m = 0; m < 4; m++)
    #pragma unroll
    for (int n = 0; n < 8; n++) acc[m][n] = (f32x4)0.f;

  #pragma unroll 1
  for (int ic0 = 0; ic0 < 512; ic0 += 64) {
    __syncthreads();
    // stage A: 128 rows x 64 ic = 1024 16B-chunks; lanes walk k-chunks within
    // a row first -> 128B contiguous global segments per 8 lanes.
    #pragma unroll
    for (int it = 0; it < 4; it++) {
      int c = it * 256 + tid, r = c >> 3, kq = c & 7;
      uint4 v = *(const uint4*)(Ag + (size_t)r * 512 + ic0 + kq * 8);
      *(uint4*)(&As[r][(kq ^ (r & 7)) * 8]) = v;
    }
    // stage B: 256 rows x 64 ic = 2048 chunks
    #pragma unroll
    for (int it = 0; it < 8; it++) {
      int c = it * 256 + tid, r = c >> 3, kq = c & 7;
      uint4 v = *(const uint4*)(Bg + (size_t)r * 512 + ic0 + kq * 8);
      *(uint4*)(&Bs[r][(kq ^ (r & 7)) * 8]) = v;
    }
    __syncthreads();
    #pragma unroll
    for (int kk = 0; kk < 2; kk++) {
      bf16x8 af[4], bfr[8];
      #pragma unroll
      for (int m = 0; m < 4; m++) {
        int r = wm * 64 + m * 16 + l15;
        af[m] = *(const bf16x8*)(&As[r][((kk * 4 + quad) ^ (r & 7)) * 8]);
      }
      #pragma unroll
      for (int n = 0; n < 8; n++) {
        int r = wn * 128 + n * 16 + l15;
        bfr[n] = *(const bf16x8*)(&Bs[r][((kk * 4 + quad) ^ (r & 7)) * 8]);
      }
      #pragma unroll
      for (int m = 0; m < 4; m++)
        #pragma unroll
        for (int n = 0; n < 8; n++)
          acc[m][n] = __builtin_amdgcn_mfma_f32_16x16x32_bf16(af[m], bfr[n], acc[m][n], 0, 0, 0);
    }
  }

  // epilogue: demod scale -> bf16 into T[bl][t][oc][px]
  const int t = mt >> 2, ocb = (mt & 3) * 128;
  float dsv[4][4];
  #pragma unroll
  for (int m = 0; m < 4; m++)
    #pragma unroll
    for (int r = 0; r < 4; r++)
      dsv[m][r] = dscale[b * 512 + ocb + wm * 64 + m * 16 + quad * 4 + r];
  const size_t Tbase = ((size_t)(bl * 9 + t)) * 512 * 1024;
  #pragma unroll
  for (int n = 0; n < 8; n++) {
    int px = nt * 256 + wn * 128 + n * 16 + l15;
    #pragma unroll
    for (int m = 0; m < 4; m++) {
      int oc = ocb + wm * 64 + m * 16 + quad * 4;
      #pragma unroll
      for (int r = 0; r < 4; r++)
        T[Tbase + (size_t)(oc + r) * 1024 + px] = f2bf(acc[m][n][r] * dsv[m][r]);
    }
  }
}

// ---- tap-sum (parity shift) + blur + noise + bias + lrelu: block per (oc,b) ----
__global__ __launch_bounds__(256) void k_blur(
    const unsigned short* __restrict__ T, const float* __restrict__ noise,
    const float* __restrict__ noise_w, const float* __restrict__ act_b,
    float* __restrict__ out, int b_base) {
  __shared__ __align__(16) unsigned short Tm[9][1024];  // 18432 B
  __shared__ unsigned short Ism[4][1089];               //  8712 B
  __shared__ float V[64][67];                           // 17152 B
  const int oc = blockIdx.x, bl = blockIdx.y, b = b_base + bl;
  // load 9 tap planes (each 1024 px, contiguous)
  for (int i = threadIdx.x; i < 1152; i += 256) {
    int tg = i >> 7, w = i & 127;
    *(uint4*)(&Tm[tg][w * 8]) =
        *(const uint4*)(T + ((size_t)(bl * 9 + tg) * 512 + oc) * 1024 + w * 8);
  }
  __syncthreads();
  // materialize parity planes: I[p][uy*33+ux] = sum of shifted taps, OOR->0
  for (int i = threadIdx.x; i < 4356; i += 256) {
    int p = i / 1089, u = i - p * 1089;
    int uy = u / 33, ux = u - uy * 33;
    int py = p >> 1, pxp = p & 1;
    float acc = 0.f;
    int na = py ? 1 : 2, nc = pxp ? 1 : 2;
    for (int a = 0; a < na; a++) {
      int ky = py ? 1 : a * 2;
      int iy = uy - (ky == 2);
      for (int c = 0; c < nc; c++) {
        int kx = pxp ? 1 : c * 2;
        int ix = ux - (kx == 2);
        if ((unsigned)iy < 32u && (unsigned)ix < 32u)
          acc += bf2f(Tm[ky * 3 + kx][iy * 32 + ix]);
      }
    }
    Ism[p][u] = f2bf(acc);
  }
  __syncthreads();
  // vertical: V[qy][px*33+ux], planes p = py*2+px
  for (int i = threadIdx.x; i < 2112; i += 256) {
    int r = i / 66, col = i - r * 66;
    int px_ = (col >= 33), ux = col - 33 * px_;
    float v0 = (r >= 1) ? bf2f(Ism[2 + px_][(r - 1) * 33 + ux]) : 0.f;
    float a_ = bf2f(Ism[px_][r * 33 + ux]);
    float b_ = bf2f(Ism[2 + px_][r * 33 + ux]);
    float c_ = bf2f(Ism[px_][(r + 1) * 33 + ux]);
    float d_ = bf2f(Ism[2 + px_][(r + 1) * 33 + ux]);
    V[2 * r][col]     = 0.25f * v0 + 0.75f * a_ + 0.75f * b_ + 0.25f * c_;
    V[2 * r + 1][col] = 0.25f * a_ + 0.75f * b_ + 0.75f * c_ + 0.25f * d_;
  }
  __syncthreads();
  const float nw = noise_w[0], ab = act_b[oc];
  for (int i = threadIdx.x; i < 2048; i += 256) {
    int qy = i >> 5, rx = i & 31;
    float w0 = (rx >= 1) ? V[qy][33 + rx - 1] : 0.f;
    float a_ = V[qy][rx];
    float b_ = V[qy][33 + rx];
    float c_ = V[qy][rx + 1];
    float d_ = V[qy][33 + rx + 1];
    float o0 = 0.25f * w0 + 0.75f * a_ + 0.75f * b_ + 0.25f * c_;
    float o1 = 0.25f * a_ + 0.75f * b_ + 0.75f * c_ + 0.25f * d_;
    const float2 nv = *(const float2*)(noise + b * 4096 + qy * 64 + 2 * rx);
    o0 += nw * nv.x + ab;  o1 += nw * nv.y + ab;
    o0 = (o0 > 0.f ? o0 : 0.2f * o0) * 1.4142135623730951f;
    o1 = (o1 > 0.f ? o1 : 0.2f * o1) * 1.4142135623730951f;
    float2 ov = make_float2(o0, o1);
    *(float2*)(out + (((size_t)b * 512 + oc) * 64 + qy) * 64 + 2 * rx) = ov;
  }
}

extern "C" void kernel_launch(void* const* d_in, const int* in_sizes, int n_in,
                              void* d_out, int out_size, void* d_ws, size_t ws_size,
                              hipStream_t stream) {
  const float* x       = (const float*)d_in[0];
  const float* style   = (const float*)d_in[1];
  const float* noise   = (const float*)d_in[2];
  const float* conv_w  = (const float*)d_in[3];
  const float* mod_w   = (const float*)d_in[4];
  const float* mod_b   = (const float*)d_in[5];
  const float* noise_w = (const float*)d_in[6];
  const float* act_b   = (const float*)d_in[7];
  float* out = (float*)d_out;

  char* ws = (char*)d_ws;
  float*          s_ws = (float*)ws;                       // 32 KB
  float*          d_sc = (float*)(ws + 32768);             // 32 KB
  float*          w2s  = (float*)(ws + 65536);             // 1 MB
  unsigned short* S2   = (unsigned short*)(ws + 65536 + 1048576);            // 16.78 MB
  unsigned short* W2   = (unsigned short*)(ws + 65536 + 1048576 + 16777216); // 4.72 MB
  unsigned short* T    = (unsigned short*)(ws + 65536 + 1048576 + 16777216 + 4718592);
  const size_t fixed  = 65536ull + 1048576ull + 16777216ull + 4718592ull;  // 22.6 MB
  const size_t t_full = (size_t)16 * 9 * 512 * 1024 * 2;                   // 151 MB

  int nb = 16;                                  // batch chunk sized to ws budget
  if (ws_size < fixed + t_full)     nb = 8;
  if (ws_size < fixed + t_full / 2) nb = 4;
  if (ws_size < fixed + t_full / 4) nb = 2;
  if (ws_size < fixed + t_full / 8) nb = 1;

  k_style<<<2048, 256, 0, stream>>>(style, mod_w, mod_b, s_ws);
  k_w2<<<512, 256, 0, stream>>>(conv_w, W2, w2s);
  k_demod<<<2048, 256, 0, stream>>>(w2s, s_ws, d_sc);
  k_xs<<<dim3(16, 8, 16), 256, 0, stream>>>(x, s_ws, S2);
  for (int b0 = 0; b0 < 16; b0 += nb) {
    k_gemm<<<dim3(36, 4, nb), 256, 0, stream>>>(S2, W2, d_sc, T, b0);
    k_blur<<<dim3(512, nb), 256, 0, stream>>>(T, noise, noise_w, act_b, out, b0);
  }
}